// Round 1
// baseline (175.604 us; speedup 1.0000x reference)
//
#include <hip/hip_runtime.h>
#include <math.h>

#define H 1024
#define L 4096
#define V 29

__device__ inline float waveReduceSum(float v) {
    #pragma unroll
    for (int off = 32; off > 0; off >>= 1)
        v += __shfl_down(v, off, 64);
    return v;
}

// K1: attn logits[l] = dot(cat1, attn_W[l]) + attn_b[l],  cat1 = [emb[tok], h0]
__global__ __launch_bounds__(256) void k1_attn_logits(
    const int* __restrict__ tok, const float* __restrict__ h0,
    const float* __restrict__ emb, const float* __restrict__ attn_W,
    const float* __restrict__ attn_b, float* __restrict__ logits)
{
    __shared__ float4 cat4[2 * H / 4];  // 2048 floats
    const int tid = threadIdx.x;
    const int t = tok[0];
    cat4[tid]       = ((const float4*)(emb + (size_t)t * H))[tid];
    cat4[256 + tid] = ((const float4*)h0)[tid];
    __syncthreads();

    const int wave = tid >> 6, lane = tid & 63;
    const int row = blockIdx.x * 4 + wave;          // 1024 blocks -> 4096 rows
    const float4* wr = (const float4*)(attn_W + (size_t)row * (2 * H));
    float acc = 0.f;
    #pragma unroll
    for (int k = 0; k < 8; ++k) {
        float4 a = wr[k * 64 + lane];
        float4 b = cat4[k * 64 + lane];
        acc += a.x * b.x + a.y * b.y + a.z * b.z + a.w * b.w;
    }
    acc = waveReduceSum(acc);
    if (lane == 0) logits[row] = acc + attn_b[row];
}

// K2: softmax over L=4096 logits -> attn_weights (written to d_out section),
//     also zeroes the attn_applied accumulator.
__global__ __launch_bounds__(1024) void k2_softmax(
    const float* __restrict__ logits, float* __restrict__ attn_w_out,
    float* __restrict__ attn_acc)
{
    __shared__ float redm[16];
    __shared__ float reds[16];
    const int tid = threadIdx.x;
    attn_acc[tid] = 0.f;

    float4 v = ((const float4*)logits)[tid];
    float m = fmaxf(fmaxf(v.x, v.y), fmaxf(v.z, v.w));
    #pragma unroll
    for (int off = 32; off > 0; off >>= 1)
        m = fmaxf(m, __shfl_down(m, off, 64));
    const int lane = tid & 63, wave = tid >> 6;
    if (lane == 0) redm[wave] = m;
    __syncthreads();
    if (tid == 0) {
        float mm = redm[0];
        #pragma unroll
        for (int i = 1; i < 16; ++i) mm = fmaxf(mm, redm[i]);
        redm[0] = mm;
    }
    __syncthreads();
    const float gmax = redm[0];

    float4 e;
    e.x = expf(v.x - gmax); e.y = expf(v.y - gmax);
    e.z = expf(v.z - gmax); e.w = expf(v.w - gmax);
    float s = e.x + e.y + e.z + e.w;
    s = waveReduceSum(s);
    if (lane == 0) reds[wave] = s;
    __syncthreads();
    if (tid == 0) {
        float ss = 0.f;
        #pragma unroll
        for (int i = 0; i < 16; ++i) ss += reds[i];
        reds[0] = ss;
    }
    __syncthreads();
    const float inv = 1.f / reds[0];
    float4 w; w.x = e.x * inv; w.y = e.y * inv; w.z = e.z * inv; w.w = e.w * inv;
    ((float4*)attn_w_out)[tid] = w;
}

// K3: attn_applied[h] = sum_l w[l] * enc[l][h]  (partial chunks + fp32 atomics)
__global__ __launch_bounds__(256) void k3_attn_applied(
    const float* __restrict__ attn_w, const float* __restrict__ enc,
    float* __restrict__ acc)
{
    const int tid = threadIdx.x;                    // float4 column index, 0..255
    const int rowStart = blockIdx.x * 16;           // 256 blocks * 16 rows = 4096
    float4 s = {0.f, 0.f, 0.f, 0.f};
    #pragma unroll 4
    for (int r = 0; r < 16; ++r) {
        const int l = rowStart + r;
        const float w = attn_w[l];
        float4 e = ((const float4*)(enc + (size_t)l * H))[tid];
        s.x += w * e.x; s.y += w * e.y; s.z += w * e.z; s.w += w * e.w;
    }
    const int c = tid * 4;
    atomicAdd(&acc[c + 0], s.x);
    atomicAdd(&acc[c + 1], s.y);
    atomicAdd(&acc[c + 2], s.z);
    atomicAdd(&acc[c + 3], s.w);
}

// K4: x[h] = relu(dot([emb[tok], attn_applied], comb_W[h]) + comb_b[h])
__global__ __launch_bounds__(256) void k4_combine(
    const int* __restrict__ tok, const float* __restrict__ emb,
    const float* __restrict__ attn_applied, const float* __restrict__ comb_W,
    const float* __restrict__ comb_b, float* __restrict__ x)
{
    __shared__ float4 cat4[2 * H / 4];
    const int tid = threadIdx.x;
    const int t = tok[0];
    cat4[tid]       = ((const float4*)(emb + (size_t)t * H))[tid];
    cat4[256 + tid] = ((const float4*)attn_applied)[tid];
    __syncthreads();

    const int wave = tid >> 6, lane = tid & 63;
    const int row = blockIdx.x * 4 + wave;          // 256 blocks -> 1024 rows
    const float4* wr = (const float4*)(comb_W + (size_t)row * (2 * H));
    float acc = 0.f;
    #pragma unroll
    for (int k = 0; k < 8; ++k) {
        float4 a = wr[k * 64 + lane];
        float4 b = cat4[k * 64 + lane];
        acc += a.x * b.x + a.y * b.y + a.z * b.z + a.w * b.w;
    }
    acc = waveReduceSum(acc);
    if (lane == 0) x[row] = fmaxf(acc + comb_b[row], 0.f);
}

// K5: gates[r] = dot(x, W_ih[r]) + b_ih[r] + dot(h0, W_hh[r]) + b_hh[r]
__global__ __launch_bounds__(256) void k5_gates(
    const float* __restrict__ x, const float* __restrict__ h0,
    const float* __restrict__ W_ih, const float* __restrict__ W_hh,
    const float* __restrict__ b_ih, const float* __restrict__ b_hh,
    float* __restrict__ gates)
{
    __shared__ float4 xs[H / 4];
    __shared__ float4 hs[H / 4];
    const int tid = threadIdx.x;
    xs[tid] = ((const float4*)x)[tid];
    hs[tid] = ((const float4*)h0)[tid];
    __syncthreads();

    const int wave = tid >> 6, lane = tid & 63;
    const int row = blockIdx.x * 4 + wave;          // 1024 blocks -> 4096 rows
    const float4* wi = (const float4*)(W_ih + (size_t)row * H);
    const float4* wh = (const float4*)(W_hh + (size_t)row * H);
    float acc = 0.f;
    #pragma unroll
    for (int k = 0; k < 4; ++k) {
        float4 a = wi[k * 64 + lane];
        float4 b = xs[k * 64 + lane];
        acc += a.x * b.x + a.y * b.y + a.z * b.z + a.w * b.w;
        float4 c = wh[k * 64 + lane];
        float4 d = hs[k * 64 + lane];
        acc += c.x * d.x + c.y * d.y + c.z * d.z + c.w * d.w;
    }
    acc = waveReduceSum(acc);
    if (lane == 0) gates[row] = acc + b_ih[row] + b_hh[row];
}

// K6: LSTM elementwise + h/c writeback + out proj + log_softmax
__global__ __launch_bounds__(1024) void k6_final(
    const float* __restrict__ gates, const float* __restrict__ c0,
    const float* __restrict__ out_W, const float* __restrict__ out_b,
    float* __restrict__ out)
{
    __shared__ float hnew[H];
    __shared__ float logit[32];
    const int tid = threadIdx.x;

    const float ig = gates[tid];
    const float fg = gates[H + tid];
    const float gg = gates[2 * H + tid];
    const float og = gates[3 * H + tid];
    const float c = c0[tid];
    const float si = 1.f / (1.f + expf(-ig));
    const float sf = 1.f / (1.f + expf(-fg));
    const float so = 1.f / (1.f + expf(-og));
    const float cn = sf * c + si * tanhf(gg);
    const float hn = so * tanhf(cn);
    out[V + tid]     = hn;   // h_new
    out[V + H + tid] = cn;   // c_new
    hnew[tid] = hn;
    __syncthreads();

    const int wave = tid >> 6, lane = tid & 63;
    for (int v = wave; v < V; v += 16) {
        const float4* wr = (const float4*)(out_W + (size_t)v * H);
        const float4* hh = (const float4*)hnew;
        float acc = 0.f;
        #pragma unroll
        for (int k = 0; k < 4; ++k) {
            float4 a = wr[k * 64 + lane];
            float4 b = hh[k * 64 + lane];
            acc += a.x * b.x + a.y * b.y + a.z * b.z + a.w * b.w;
        }
        acc = waveReduceSum(acc);
        if (lane == 0) logit[v] = acc + out_b[v];
    }
    __syncthreads();

    if (tid < 64) {
        const float val = (tid < V) ? logit[tid] : -3.4e38f;
        float m = val;
        #pragma unroll
        for (int off = 32; off > 0; off >>= 1)
            m = fmaxf(m, __shfl_down(m, off, 64));
        m = __shfl(m, 0, 64);
        float e = (tid < V) ? expf(val - m) : 0.f;
        float s = e;
        #pragma unroll
        for (int off = 32; off > 0; off >>= 1)
            s += __shfl_down(s, off, 64);
        s = __shfl(s, 0, 64);
        if (tid < V) out[tid] = val - m - logf(s);
    }
}

extern "C" void kernel_launch(void* const* d_in, const int* in_sizes, int n_in,
                              void* d_out, int out_size, void* d_ws, size_t ws_size,
                              hipStream_t stream) {
    const int*   tok    = (const int*)  d_in[0];
    const float* h0     = (const float*)d_in[1];
    const float* c0     = (const float*)d_in[2];
    const float* enc    = (const float*)d_in[3];
    const float* emb    = (const float*)d_in[4];
    const float* attn_W = (const float*)d_in[5];
    const float* attn_b = (const float*)d_in[6];
    const float* comb_W = (const float*)d_in[7];
    const float* comb_b = (const float*)d_in[8];
    const float* W_ih   = (const float*)d_in[9];
    const float* W_hh   = (const float*)d_in[10];
    const float* b_ih   = (const float*)d_in[11];
    const float* b_hh   = (const float*)d_in[12];
    const float* out_W  = (const float*)d_in[13];
    const float* out_b  = (const float*)d_in[14];

    float* out = (float*)d_out;
    float* ws  = (float*)d_ws;
    float* logits   = ws;                 // 4096
    float* attn_acc = ws + 4096;          // 1024
    float* x        = ws + 5120;          // 1024
    float* gates    = ws + 6144;          // 4096
    float* attn_w_out = out + V + 2 * H;  // attn_weights section of d_out

    k1_attn_logits<<<1024, 256, 0, stream>>>(tok, h0, emb, attn_W, attn_b, logits);
    k2_softmax<<<1, 1024, 0, stream>>>(logits, attn_w_out, attn_acc);
    k3_attn_applied<<<256, 256, 0, stream>>>(attn_w_out, enc, attn_acc);
    k4_combine<<<256, 256, 0, stream>>>(tok, emb, attn_acc, comb_W, comb_b, x);
    k5_gates<<<1024, 256, 0, stream>>>(x, h0, W_ih, W_hh, b_ih, b_hh, gates);
    k6_final<<<1, 1024, 0, stream>>>(gates, c0, out_W, out_b, out);
}